// Round 7
// baseline (4358.987 us; speedup 1.0000x reference)
//
#include <hip/hip_runtime.h>
#include <math.h>

#define NSWEEP_MAX 16
#define T2_TOL 2e-9f    // exit when max dpq^2/(dpp*dqq) below this
#define EPS2 1e-10f     // lambda clamp 1e-5 => lambda^2 clamp 1e-10

// One-sided Jacobi on G = S (SPD): orthogonalize columns; at convergence
// G = U diag(lambda), U = eigenvectors, lambda = column norms. One 64-lane
// wave per matrix; lane l holds column l in 64 VGPRs. XOR pairing: round m
// rotates pairs {l, l^m}.
//
// Per round the partner column is fetched ONCE (64 ds_bpermute) and must
// stay live across the dot -> rotation-coeff -> rotate sequence. LLVM
// considers ds_bpermute trivially rematerializable (its source g[s] is
// still live at the rotate's use site), so with plain code the allocator
// chooses 80 VGPRs + a SECOND 64-bpermute pass (measured rounds 5/6:
// VGPR_Count=80, ~130 LDS ops/round). The empty asm below makes an
// inline-asm the producer of pr[s]; inline asm is never remat'd, forcing
// the 64 values to stay resident (~150 VGPR) and halving LDS-pipe traffic.
//
// TIE-SAFE rotation: both lanes of a pair evaluate the rotation in the
// CANONICAL orientation (low-lane = "p"): tau = (d_hi - d_lo) * rcp(2*dpq).
// Operands and order identical on both lanes -> bitwise-identical
// tau/tt/cc/ss; only the application sign differs:
//   es    = isLow ? -ss : +ss     (g' = cc*g_own + es*g_partner)
//   t_own = isLow ? +tt : -tt     (dpp' = dpp - t_own*dpq)

__device__ __forceinline__ float bperm_f(int idx, float x) {
    return __int_as_float(__builtin_amdgcn_ds_bpermute(idx, __float_as_int(x)));
}
__device__ __forceinline__ float rdlane_f(float x, int l) {
    return __int_as_float(__builtin_amdgcn_readlane(__float_as_int(x), l));
}

__global__ __launch_bounds__(64, 2) void spdlog_onesided(
    const float* __restrict__ S, float* __restrict__ Out, int nmat) {
    __shared__ float X[64][64];  // 16 KB, reconstruction only
    const int lane = threadIdx.x;
    const int b = blockIdx.x;
    if (b >= nmat) return;
    const float* Sb = S + (size_t)b * 4096;
    float* Ob = Out + (size_t)b * 4096;

    // ---- load column `lane`: g[s] = S[s][lane] (coalesced across lanes)
    float g[64];
    #pragma unroll 64
    for (int s = 0; s < 64; ++s) g[s] = Sb[s * 64 + lane];

    float dpp = 0.0f;

    #pragma unroll 1
    for (int sweep = 0; sweep < NSWEEP_MAX; ++sweep) {
        // refresh Gram diagonal from actual column (kills drift)
        dpp = 0.0f;
        #pragma unroll 64
        for (int s = 0; s < 64; ++s) dpp = fmaf(g[s], g[s], dpp);

        float maxt2 = 0.0f;
        #pragma unroll 1
        for (int m = 1; m < 64; ++m) {
            const int xl = lane ^ m;
            const int idx = xl << 2;
            const bool isLow = lane < xl;
            // ---- phase 1: fetch partner column ONCE, lane-local dot.
            // fma(a,b,c)==fma(b,a,c) bitwise -> dpq identical on both lanes.
            float pr[64];
            float dpq = 0.0f;
            #pragma unroll 64
            for (int s = 0; s < 64; ++s) {
                pr[s] = bperm_f(idx, g[s]);
                dpq = fmaf(g[s], pr[s], dpq);
            }
            // Force pr[] live: inline asm is not rematerializable, so the
            // rotate below cannot be fed by a second bpermute pass.
            #pragma unroll 64
            for (int s = 0; s < 64; ++s) asm("" : "+v"(pr[s]));
            const float pd = bperm_f(idx, dpp);
            const float d_lo = isLow ? dpp : pd;
            const float d_hi = isLow ? pd : dpp;
            // convergence metric (relative Gram off-diagonal, pre-rotation)
            const float t2 = dpq * dpq * __builtin_amdgcn_rcpf(dpp * pd);
            maxt2 = fmaxf(maxt2, t2);
            // ---- canonical rotation (identical bits on both lanes)
            const float tau = (d_hi - d_lo) * __builtin_amdgcn_rcpf(2.0f * dpq);
            const float sq = __builtin_amdgcn_sqrtf(fmaf(tau, tau, 1.0f));
            float tt = __builtin_amdgcn_rcpf(fabsf(tau) + sq);
            tt = copysignf(tt, tau);
            float cc = __builtin_amdgcn_rsqf(fmaf(tt, tt, 1.0f));
            float ss = tt * cc;
            const bool tiny = fabsf(dpq) < 1e-30f;
            cc = tiny ? 1.0f : cc;
            ss = tiny ? 0.0f : ss;
            tt = tiny ? 0.0f : tt;
            const float es = isLow ? -ss : ss;
            const float t_own = isLow ? tt : -tt;
            dpp = fmaf(-t_own, dpq, dpp);  // exact diagonal Gram update
            // ---- phase 2: register-only rotate (uses the LIVE pr[])
            #pragma unroll 64
            for (int s = 0; s < 64; ++s) g[s] = fmaf(cc, g[s], es * pr[s]);
        }
        // ---- wave max of maxt2
        maxt2 = fmaxf(maxt2, __shfl_xor(maxt2, 1));
        maxt2 = fmaxf(maxt2, __shfl_xor(maxt2, 2));
        maxt2 = fmaxf(maxt2, __shfl_xor(maxt2, 4));
        maxt2 = fmaxf(maxt2, __shfl_xor(maxt2, 8));
        maxt2 = fmaxf(maxt2, __shfl_xor(maxt2, 16));
        maxt2 = fmaxf(maxt2, __shfl_xor(maxt2, 32));
        if (maxt2 < T2_TOL) break;  // wave-uniform
    }

    // ---- fresh column norm^2 -> eigenvalue; clamp matches ref (on lambda)
    float dfin = 0.0f;
    #pragma unroll 64
    for (int s = 0; s < 64; ++s) dfin = fmaf(g[s], g[s], dfin);
    const float w = 0.5f * logf(fmaxf(dfin, EPS2));
    const float rs = __builtin_amdgcn_rsqf(fmaxf(dfin, 1e-20f));

    // ---- reconstruction: O = U diag(w) U^T, U columns = g*rs
    #pragma unroll 64
    for (int s = 0; s < 64; ++s) X[s][lane] = g[s] * rs;  // lane-private col
    __syncthreads();
    float uw[64];
    {
        const float4* rowp = (const float4*)&X[lane][0];  // own row of U
        #pragma unroll 16
        for (int gq = 0; gq < 16; ++gq) {
            const float4 q = rowp[gq];
            uw[4 * gq + 0] = q.x;
            uw[4 * gq + 1] = q.y;
            uw[4 * gq + 2] = q.z;
            uw[4 * gq + 3] = q.w;
        }
    }
    #pragma unroll 64
    for (int c = 0; c < 64; ++c) uw[c] *= rdlane_f(w, c);
    #pragma unroll 2
    for (int i = 0; i < 64; ++i) {
        const float4* Urow = (const float4*)&X[i][0];  // wave-uniform: bcast
        float acc = 0.0f;
        #pragma unroll 16
        for (int gq = 0; gq < 16; ++gq) {
            const float4 q = Urow[gq];
            acc = fmaf(q.x, uw[4 * gq + 0], acc);
            acc = fmaf(q.y, uw[4 * gq + 1], acc);
            acc = fmaf(q.z, uw[4 * gq + 2], acc);
            acc = fmaf(q.w, uw[4 * gq + 3], acc);
        }
        Ob[i * 64 + lane] = acc;
    }
}

extern "C" void kernel_launch(void* const* d_in, const int* in_sizes, int n_in,
                              void* d_out, int out_size, void* d_ws, size_t ws_size,
                              hipStream_t stream) {
    const float* S = (const float*)d_in[0];
    float* Out = (float*)d_out;
    const int nmat = in_sizes[0] / 4096;
    spdlog_onesided<<<nmat, 64, 0, stream>>>(S, Out, nmat);
}